// Round 10
// baseline (12295.984 us; speedup 1.0000x reference)
//
#include <hip/hip_runtime.h>
#include <stdint.h>
#include <math.h>

#define HH   512
#define BB   64
#define TT   2000
#define NEXC 409          // int(0.8 * 512)
#define SL   16           // hidden units per slice (32 slices)
#define NBAT 8            // batches multiplexed per block
#define NBLK 256          // 8 groups x 32 slices = full machine
#define PUBH ((size_t)(BB * HH))

// Python-float constants, rounded to f32 exactly as the reference does.
constexpr float ALPHA_F     = 0.1f;
constexpr float IN_SCALE_F  = (float)4.4721359549995794e-03;
constexpr float REC_SCALE_F = (float)4.4721359549995794e-02;
constexpr float SQRT2_F     = 1.41421356237309515f;
constexpr float U_LO        = -0x1.fffffep-1f;

struct U2 { uint32_t a, b; };

__host__ __device__ constexpr uint32_t rotl32(uint32_t x, int d) {
  return (x << d) | (x >> (32 - d));
}

// JAX Threefry-2x32, 20 rounds.
__host__ __device__ constexpr U2 tf2x32(uint32_t k0, uint32_t k1,
                                        uint32_t x0, uint32_t x1) {
  uint32_t ks[3] = {k0, k1, k0 ^ k1 ^ 0x1BD11BDAu};
  const int R[2][4] = {{13, 15, 26, 6}, {17, 29, 16, 24}};
  x0 += ks[0]; x1 += ks[1];
  for (int g = 0; g < 5; ++g) {
    const int* r = R[g & 1];
    for (int i = 0; i < 4; ++i) { x0 += x1; x1 = rotl32(x1, r[i]); x1 ^= x0; }
    x0 += ks[(g + 1) % 3];
    x1 += ks[(g + 2) % 3] + (uint32_t)(g + 1);
  }
  return U2{x0, x1};
}

constexpr U2 KIN_  = tf2x32(0u, 42u, 0u, 0u);
constexpr U2 KREC_ = tf2x32(0u, 42u, 0u, 1u);
constexpr uint32_t KIN0 = KIN_.a,  KIN1 = KIN_.b;
constexpr uint32_t KRC0 = KREC_.a, KRC1 = KREC_.b;

__device__ __forceinline__ float jax_normal(uint32_t k0, uint32_t k1, uint32_t idx) {
  U2 o = tf2x32(k0, k1, 0u, idx);
  uint32_t bits = o.a ^ o.b;
  float f = __uint_as_float((bits >> 9) | 0x3f800000u) - 1.0f;  // [0,1)
  float u = fmaxf(U_LO, f * 2.0f + U_LO);
  float w = -log1pf(-u * u);
  float p;
  if (w < 5.0f) {
    w = w - 2.5f;
    p =             2.81022636e-08f;
    p = fmaf(p, w,  3.43273939e-07f);
    p = fmaf(p, w, -3.5233877e-06f);
    p = fmaf(p, w, -4.39150654e-06f);
    p = fmaf(p, w,  0.00021858087f);
    p = fmaf(p, w, -0.00125372503f);
    p = fmaf(p, w, -0.00417768164f);
    p = fmaf(p, w,  0.246640727f);
    p = fmaf(p, w,  1.50140941f);
  } else {
    w = sqrtf(w) - 3.0f;
    p =            -0.000200214257f;
    p = fmaf(p, w,  0.000100950558f);
    p = fmaf(p, w,  0.00134934322f);
    p = fmaf(p, w, -0.00367342844f);
    p = fmaf(p, w,  0.00573950773f);
    p = fmaf(p, w, -0.0076224613f);
    p = fmaf(p, w,  0.00943887047f);
    p = fmaf(p, w,  1.00167406f);
    p = fmaf(p, w,  2.83297682f);
  }
  return SQRT2_F * (p * u);
}

// Workspace: pub[2][BB][HH] uint64, word = (tag << 32) | f32bits(relu(h)).
// tag t+1 = value after step t; slot parity = tag & 1. MALL (agent scope).
#define PUB_BYTES (2 * BB * HH * 8)   // 512 KB

// LDS-only barrier: publish stores stay in flight (nobody locally waits on them).
__device__ __forceinline__ void barrier_lds() {
  asm volatile("s_waitcnt lgkmcnt(0)" ::: "memory");
  __builtin_amdgcn_s_barrier();
  asm volatile("" ::: "memory");
}

__device__ __forceinline__ uint64_t pub_ld(const uint64_t* a) {
  return __hip_atomic_load(a, __ATOMIC_RELAXED, __HIP_MEMORY_SCOPE_AGENT);
}

// One phase = one step of batch Q (constexpr). RVQ/PREQ/PREPF are register
// NAMES (static indexing only). PREPF = pre[(Q+4)&7]: the covering load for
// the batch published 4 phases ago, consumed 4 phases later.
#define PHASE(Q, RVQ, PREQ, PREPF)                                            \
  {                                                                           \
    const int bQ   = b0 + (Q);                                                \
    const int par_ = (Q) & 1;                                                 \
    if (t > 0) {                                                              \
      if (isOwnGrp) {                                                         \
        RVQ = rloc[(Q)][tid - ownLo];                                         \
      } else {                                                                \
        uint64_t w_ = PREQ;                                                   \
        if ((uint32_t)(w_ >> 32) != (uint32_t)t) {                            \
          const uint64_t* a_ = pub + ((t & 1) ? PUBH : 0)                     \
                               + (size_t)bQ * HH + tid;                       \
          do {                                                                \
            __builtin_amdgcn_s_sleep(1);                                      \
            w_ = pub_ld(a_);                                                  \
          } while ((uint32_t)(w_ >> 32) != (uint32_t)t);                      \
        }                                                                     \
        RVQ = __uint_as_float((uint32_t)w_);                                  \
      }                                                                       \
      if (duty) {  /* out[bQ][t-1] from tag-t rv, off other blocks' path */   \
        float v_ = RVQ * who_f;                                               \
        for (int o_ = 32; o_ > 0; o_ >>= 1) v_ += __shfl_down(v_, o_);        \
        if (lane == 0) obufd[par_][wv] = v_;                                  \
      }                                                                       \
    }                                                                         \
    /* matvec: wave wv = i-chunk wv; lane's column = ownLo + (lane & 15);     \
       64 ascending FMAs -> bit-identical chunk order to all passing runs. */ \
    {                                                                         \
      float acc_ = 0.0f;                                                      \
      _Pragma("unroll")                                                       \
      for (int k_ = 0; k_ < 64; ++k_) {                                       \
        float rk_ = __uint_as_float(                                          \
            __builtin_amdgcn_readlane(__float_as_uint(RVQ), k_));             \
        acc_ = fmaf(rk_, wJ[k_], acc_);                                       \
      }                                                                       \
      if (lane < SL) red[par_][wv][lane] = acc_;                              \
    }                                                                         \
    barrier_lds();  /* the only barrier per phase */                          \
    if ((tid >> 4) == (Q)) {  /* 16 owner threads of batch Q */               \
      const int jl = tid & 15;                                                \
      float acc = red[par_][0][jl];                                           \
      _Pragma("unroll")                                                       \
      for (int c_ = 1; c_ < 8; ++c_) acc += red[par_][c_][jl];                \
      float nr  = nbuf[t & 3][(Q)][jl];                                       \
      float ni0 = ninb[t & 3][(Q)][0];                                        \
      float ni1 = ninb[t & 3][(Q)][1];                                        \
      float hid_hid = acc + bhh + REC_SCALE_F * nr;                           \
      float cur0 = fmaxf(xs + IN_SCALE_F * ni0, 0.0f);                        \
      float cur1 = fmaxf(xc + IN_SCALE_F * ni1, 0.0f);                        \
      float hid_in = cur0 * wih0 + cur1 * wih1;                               \
      h = h + (-h + hid_in + hid_hid) * ALPHA_F;                              \
      float r_ = fmaxf(h, 0.0f);                                              \
      __hip_atomic_store(pub + (((t + 1) & 1) ? PUBH : 0)                     \
                             + (size_t)bQ * HH + ownLo + jl,                  \
                         ((uint64_t)(uint32_t)(t + 1) << 32) |                \
                             (uint64_t)__float_as_uint(r_),                   \
                         __ATOMIC_RELAXED, __HIP_MEMORY_SCOPE_AGENT);         \
      rloc[(Q)][jl] = r_;                                                     \
      __builtin_nontemporal_store(h, hids + ((size_t)bQ * TT + t) * HH        \
                                        + ownLo + jl);                        \
      xs = xs_n; xc = xc_n;          /* rotate input prefetch (t+1 ready) */  \
      if (t + 2 < TT) {                                                       \
        xs_n = i_stim[bQ * TT + (t + 2)];                                     \
        xc_n = i_cc[bQ * TT + (t + 2)];                                       \
      }                                                                       \
    }                                                                         \
    if (t > 0 && duty && tid == finTid) {                                     \
      const float* ob = obufd[par_];                                          \
      float p_ = ((ob[0] + ob[1]) + (ob[2] + ob[3])) +                        \
                 ((ob[4] + ob[5]) + (ob[6] + ob[7]));                         \
      outs[bQ * TT + (t - 1)] = p_ + bho;                                     \
    }                                                                         \
    {  /* covering prefetch: batch (Q+4)&7, published 4 phases ago */         \
      const uint32_t tau_ = ((Q) >= 4) ? (uint32_t)(t + 1) : (uint32_t)t;     \
      PREPF = pub_ld(pub + ((tau_ & 1) ? PUBH : 0)                            \
                     + (size_t)(b0 + (((Q) + 4) & 7)) * HH + tid);            \
    }                                                                         \
  }

#define TAILC(Q, RVQ, PREQ)                                                   \
  {                                                                           \
    const int bQ = b0 + (Q);                                                  \
    if (isOwnGrp) {                                                           \
      RVQ = rloc[(Q)][tid - ownLo];                                           \
    } else {                                                                  \
      uint64_t w_ = PREQ;                                                     \
      if ((uint32_t)(w_ >> 32) != (uint32_t)TT) {                             \
        const uint64_t* a_ = pub + ((TT & 1) ? PUBH : 0)                      \
                             + (size_t)bQ * HH + tid;                         \
        do {                                                                  \
          __builtin_amdgcn_s_sleep(1);                                        \
          w_ = pub_ld(a_);                                                    \
        } while ((uint32_t)(w_ >> 32) != (uint32_t)TT);                       \
      }                                                                       \
      RVQ = __uint_as_float((uint32_t)w_);                                    \
    }                                                                         \
    float v_ = RVQ * who_f;                                                   \
    for (int o_ = 32; o_ > 0; o_ >>= 1) v_ += __shfl_down(v_, o_);            \
    if (lane == 0) obufd[0][wv] = v_;                                         \
    __syncthreads();                                                          \
    if (tid == finTid) {                                                      \
      const float* ob = obufd[0];                                             \
      float p_ = ((ob[0] + ob[1]) + (ob[2] + ob[3])) +                        \
                 ((ob[4] + ob[5]) + (ob[6] + ob[7]));                         \
      outs[bQ * TT + (TT - 1)] = p_ + bho;                                    \
    }                                                                         \
    __syncthreads();                                                          \
  }

__global__ __launch_bounds__(512, 2)
void zrnn_main(const float* __restrict__ i_stim, const float* __restrict__ i_cc,
               const float* __restrict__ hidden0,
               const float* __restrict__ w_ih, const float* __restrict__ w_hh,
               const float* __restrict__ b_hh,
               const float* __restrict__ w_ho, const float* __restrict__ b_ho,
               float* __restrict__ outs, float* __restrict__ hids,
               uint64_t* __restrict__ pub) {
  // bid -> (group g = bid&7 -> batches 8g..8g+7, slice s = bid>>3 -> units
  // [16s, 16s+16)). Group's 32 blocks share bid&7 -> one XCD under
  // round-robin dispatch (perf hint only; exchange goes through MALL).
  const int bid  = blockIdx.x;
  const int g    = bid & 7;
  const int s    = bid >> 3;
  const int b0   = g * NBAT;
  const int tid  = threadIdx.x;
  const int lane = tid & 63;
  const int wv   = tid >> 6;

  const int  ownLo    = s * SL;
  const bool isOwnGrp = (tid >= ownLo) && (tid < ownLo + SL);
  const int  finTid   = 496;   // non-owner, non-generator finalizer

  __shared__ float red[2][8][SL];     // phase-parity matvec partials
  __shared__ float rloc[NBAT][SL];    // own-slice relu(h) fast path
  __shared__ float nbuf[4][NBAT][SL]; // n_rec, generated 2 rounds ahead
  __shared__ float ninb[4][NBAT][2];  // n_in
  __shared__ float obufd[2][8];       // duty output partials (phase parity)

  // Weights: thread (wv, lane) holds wt[i][j] for i in [64wv, 64wv+64),
  // j = ownLo + (lane & 15)  (lanes 16+ replicate lanes 0-15's columns).
  // wt[i][j] = |w_hh[j][i]| * (i != j) * ei[i]. Batch-invariant.
  const int jA = ownLo + (lane & 15);
  const int i0 = wv * 64;
  float wJ[64];
  #pragma unroll
  for (int k4 = 0; k4 < 16; ++k4) {
    float4 a4 = *reinterpret_cast<const float4*>(&w_hh[jA * HH + i0 + k4 * 4]);
    const float av[4] = {a4.x, a4.y, a4.z, a4.w};
    #pragma unroll
    for (int c = 0; c < 4; ++c) {
      const int i = i0 + k4 * 4 + c;
      float va = (i == jA) ? 0.0f : fabsf(av[c]);
      wJ[k4 * 4 + c] = (i < NEXC) ? va : -va;
    }
  }

  // Owners: thread tid < 128 owns (batch q = tid>>4, unit j = ownLo + (tid&15)).
  float h = 0.f, wih0 = 0.f, wih1 = 0.f, bhh = 0.f;
  float xs = 0.f, xc = 0.f, xs_n = 0.f, xc_n = 0.f;
  if (tid < NBAT * SL) {
    const int oq = tid >> 4, jl = tid & 15;
    const int jg = ownLo + jl, bq = b0 + oq;
    h    = hidden0[bq * HH + jg];
    wih0 = w_ih[jg * 2 + 0];
    wih1 = w_ih[jg * 2 + 1];
    bhh  = b_hh[jg];
    xs   = i_stim[bq * TT + 0];
    xc   = i_cc[bq * TT + 0];
    xs_n = i_stim[bq * TT + 1];
    xc_n = i_cc[bq * TT + 1];
  }
  const float who_f = w_ho[tid];
  const float bho   = b_ho[0];

  // rv registers: thread tid holds relu(h[i = tid]) for each batch.
  float rv0 = fmaxf(hidden0[(b0 + 0) * HH + tid], 0.f);
  float rv1 = fmaxf(hidden0[(b0 + 1) * HH + tid], 0.f);
  float rv2 = fmaxf(hidden0[(b0 + 2) * HH + tid], 0.f);
  float rv3 = fmaxf(hidden0[(b0 + 3) * HH + tid], 0.f);
  float rv4 = fmaxf(hidden0[(b0 + 4) * HH + tid], 0.f);
  float rv5 = fmaxf(hidden0[(b0 + 5) * HH + tid], 0.f);
  float rv6 = fmaxf(hidden0[(b0 + 6) * HH + tid], 0.f);
  float rv7 = fmaxf(hidden0[(b0 + 7) * HH + tid], 0.f);

  // Noise prefill for rounds 0,1 (slots 0,1). Generators: tids 128-255 (n_rec),
  // 256-271 (n_in). Owner threads never touch threefry in the loop.
  if (tid >= 128 && tid < 256) {
    const int e = tid - 128, qn = e >> 4, jn = e & 15;
    #pragma unroll
    for (int tp = 0; tp < 2; ++tp)
      nbuf[tp][qn][jn] = jax_normal(KRC0, KRC1,
          (uint32_t)tp * (uint32_t)(BB * HH) +
          (uint32_t)((b0 + qn) * HH + ownLo + jn));
  } else if (tid >= 256 && tid < 272) {
    const int e = tid - 256, qn = e >> 1, sl = e & 1;
    #pragma unroll
    for (int tp = 0; tp < 2; ++tp)
      ninb[tp][qn][sl] = jax_normal(KIN0, KIN1,
          (uint32_t)(tp * (BB * 2) + (b0 + qn) * 2 + sl));
  }

  uint64_t pre0 = 0, pre1 = 0, pre2 = 0, pre3 = 0;
  uint64_t pre4 = 0, pre5 = 0, pre6 = 0, pre7 = 0;

  __syncthreads();

  for (int t = 0; t < TT; ++t) {
    const bool duty = (t > 0) && (s == ((t - 1) & 31));

    PHASE(0, rv0, pre0, pre4)
    // Noise for round t+2 during phase-0 slack (slot (t+2)&3 disjoint from
    // this round's reads of slot t&3 and next round's (t+1)&3).
    if (t + 2 < TT) {
      if (tid >= 128 && tid < 256) {
        const int e = tid - 128, qn = e >> 4, jn = e & 15;
        nbuf[(t + 2) & 3][qn][jn] = jax_normal(KRC0, KRC1,
            (uint32_t)(t + 2) * (uint32_t)(BB * HH) +
            (uint32_t)((b0 + qn) * HH + ownLo + jn));
      } else if (tid >= 256 && tid < 272) {
        const int e = tid - 256, qn = e >> 1, sl = e & 1;
        ninb[(t + 2) & 3][qn][sl] = jax_normal(KIN0, KIN1,
            (uint32_t)((t + 2) * (BB * 2) + (b0 + qn) * 2 + sl));
      }
    }
    PHASE(1, rv1, pre1, pre5)
    PHASE(2, rv2, pre2, pre6)
    PHASE(3, rv3, pre3, pre7)
    PHASE(4, rv4, pre4, pre0)
    PHASE(5, rv5, pre5, pre1)
    PHASE(6, rv6, pre6, pre2)
    PHASE(7, rv7, pre7, pre3)
  }

  // Tail: outs[.][TT-1] needs tag TT; duty slice (TT-1)&31 only.
  __syncthreads();
  if (s == ((TT - 1) & 31)) {
    TAILC(0, rv0, pre0)
    TAILC(1, rv1, pre1)
    TAILC(2, rv2, pre2)
    TAILC(3, rv3, pre3)
    TAILC(4, rv4, pre4)
    TAILC(5, rv5, pre5)
    TAILC(6, rv6, pre6)
    TAILC(7, rv7, pre7)
  }
}

extern "C" void kernel_launch(void* const* d_in, const int* in_sizes, int n_in,
                              void* d_out, int out_size, void* d_ws, size_t ws_size,
                              hipStream_t stream) {
  const float* i_stim = (const float*)d_in[0];
  const float* i_cc   = (const float*)d_in[1];
  const float* hidden = (const float*)d_in[2];
  const float* w_ih   = (const float*)d_in[3];
  // d_in[4] = b_ih — never used by the reference
  const float* w_hh   = (const float*)d_in[5];
  const float* b_hh   = (const float*)d_in[6];
  const float* w_ho   = (const float*)d_in[7];
  const float* b_ho   = (const float*)d_in[8];

  float* outs   = (float*)d_out;                     // [B,T,O]
  float* hids   = (float*)d_out + (size_t)BB * TT;   // [B,T,H]
  uint64_t* pub = (uint64_t*)d_ws;

  // Kill stale tags from previous graph replays (tags strictly increase
  // within a run, so zeroed words can never falsely match).
  hipMemsetAsync(pub, 0, PUB_BYTES, stream);

  void* args[] = {(void*)&i_stim, (void*)&i_cc, (void*)&hidden, (void*)&w_ih,
                  (void*)&w_hh, (void*)&b_hh, (void*)&w_ho, (void*)&b_ho,
                  (void*)&outs, (void*)&hids, (void*)&pub};
  hipLaunchCooperativeKernel((const void*)zrnn_main, dim3(NBLK), dim3(512),
                             args, 0, stream);
}

// Round 11
// 9560.925 us; speedup vs baseline: 1.2861x; 1.2861x over previous
//
#include <hip/hip_runtime.h>
#include <stdint.h>
#include <math.h>

#define HH   512
#define BB   64
#define TT   2000
#define NEXC 409          // int(0.8 * 512)
#define SL   32           // hidden units (columns) per slice; 16 slices
#define NBAT 4            // batches multiplexed per block (latency hiding)
#define NBLK 256          // 16 groups x 16 slices = full machine
#define PUBH ((size_t)(BB * HH))

// Python-float constants, rounded to f32 exactly as the reference does.
constexpr float ALPHA_F     = 0.1f;
constexpr float IN_SCALE_F  = (float)4.4721359549995794e-03;
constexpr float REC_SCALE_F = (float)4.4721359549995794e-02;
constexpr float SQRT2_F     = 1.41421356237309515f;
constexpr float U_LO        = -0x1.fffffep-1f;

struct U2 { uint32_t a, b; };

__host__ __device__ constexpr uint32_t rotl32(uint32_t x, int d) {
  return (x << d) | (x >> (32 - d));
}

// JAX Threefry-2x32, 20 rounds.
__host__ __device__ constexpr U2 tf2x32(uint32_t k0, uint32_t k1,
                                        uint32_t x0, uint32_t x1) {
  uint32_t ks[3] = {k0, k1, k0 ^ k1 ^ 0x1BD11BDAu};
  const int R[2][4] = {{13, 15, 26, 6}, {17, 29, 16, 24}};
  x0 += ks[0]; x1 += ks[1];
  for (int g = 0; g < 5; ++g) {
    const int* r = R[g & 1];
    for (int i = 0; i < 4; ++i) { x0 += x1; x1 = rotl32(x1, r[i]); x1 ^= x0; }
    x0 += ks[(g + 1) % 3];
    x1 += ks[(g + 2) % 3] + (uint32_t)(g + 1);
  }
  return U2{x0, x1};
}

constexpr U2 KIN_  = tf2x32(0u, 42u, 0u, 0u);
constexpr U2 KREC_ = tf2x32(0u, 42u, 0u, 1u);
constexpr uint32_t KIN0 = KIN_.a,  KIN1 = KIN_.b;
constexpr uint32_t KRC0 = KREC_.a, KRC1 = KREC_.b;

__device__ __forceinline__ float jax_normal(uint32_t k0, uint32_t k1, uint32_t idx) {
  U2 o = tf2x32(k0, k1, 0u, idx);
  uint32_t bits = o.a ^ o.b;
  float f = __uint_as_float((bits >> 9) | 0x3f800000u) - 1.0f;  // [0,1)
  float u = fmaxf(U_LO, f * 2.0f + U_LO);
  float w = -log1pf(-u * u);
  float p;
  if (w < 5.0f) {
    w = w - 2.5f;
    p =             2.81022636e-08f;
    p = fmaf(p, w,  3.43273939e-07f);
    p = fmaf(p, w, -3.5233877e-06f);
    p = fmaf(p, w, -4.39150654e-06f);
    p = fmaf(p, w,  0.00021858087f);
    p = fmaf(p, w, -0.00125372503f);
    p = fmaf(p, w, -0.00417768164f);
    p = fmaf(p, w,  0.246640727f);
    p = fmaf(p, w,  1.50140941f);
  } else {
    w = sqrtf(w) - 3.0f;
    p =            -0.000200214257f;
    p = fmaf(p, w,  0.000100950558f);
    p = fmaf(p, w,  0.00134934322f);
    p = fmaf(p, w, -0.00367342844f);
    p = fmaf(p, w,  0.00573950773f);
    p = fmaf(p, w, -0.0076224613f);
    p = fmaf(p, w,  0.00943887047f);
    p = fmaf(p, w,  1.00167406f);
    p = fmaf(p, w,  2.83297682f);
  }
  return SQRT2_F * (p * u);
}

// Workspace: pub[2][BB][HH] uint64, word = (tag << 32) | f32bits(relu(h)).
// tag t+1 = value after step t; slot parity = tag & 1. MALL (agent scope).
#define PUB_BYTES (2 * BB * HH * 8)   // 512 KB

// LDS-only barrier: publish stores stay in flight (nobody locally waits).
__device__ __forceinline__ void barrier_lds() {
  asm volatile("s_waitcnt lgkmcnt(0)" ::: "memory");
  __builtin_amdgcn_s_barrier();
  asm volatile("" ::: "memory");
}

__device__ __forceinline__ uint64_t pub_ld(const uint64_t* a) {
  return __hip_atomic_load(a, __ATOMIC_RELAXED, __HIP_MEMORY_SCOPE_AGENT);
}

// Noise for round t+2, generated once per round in phase 0 by dedicated
// threads (128-263). Slot (t+2)&3 is disjoint from reads of t&3 / (t+1)&3.
#define NOISE_IF_PHASE0(Q)                                                    \
  if ((Q) == 0 && t + 2 < TT) {                                               \
    if (tid >= 128 && tid < 256) {                                            \
      const int e_ = tid - 128, qn_ = e_ >> 5, jn_ = e_ & 31;                 \
      nbuf[(t + 2) & 3][qn_][jn_] = jax_normal(KRC0, KRC1,                    \
          (uint32_t)(t + 2) * (uint32_t)(BB * HH) +                           \
          (uint32_t)((b0 + qn_) * HH + ownLo + jn_));                         \
    } else if (tid >= 256 && tid < 264) {                                     \
      const int e_ = tid - 256, qn_ = e_ >> 1, sl_ = e_ & 1;                  \
      ninb[(t + 2) & 3][qn_][sl_] = jax_normal(KIN0, KIN1,                    \
          (uint32_t)((t + 2) * (BB * 2) + (b0 + qn_) * 2 + sl_));             \
    }                                                                         \
  }

// One phase = one step of batch Q (constexpr). RVQ/PREQ are register NAMES
// (static indexing only). PREPF = pre[(Q+2)&3]: prefetch issued 2 phases
// before its consume, >= ~1.5k cyc after the matching publish.
#define PHASE(Q, RVQ, PREQ, PREPF)                                            \
  {                                                                           \
    const int bQ = b0 + (Q);                                                  \
    if (t > 0) {                                                              \
      if (isOwnSlice) {                                                       \
        RVQ = rloc[(Q)][tid - ownLo];                                         \
      } else {                                                                \
        uint64_t w_ = PREQ;                                                   \
        if ((uint32_t)(w_ >> 32) != (uint32_t)t) {                            \
          const uint64_t* a_ = pub + ((t & 1) ? PUBH : 0)                     \
                               + (size_t)bQ * HH + tid;                       \
          w_ = pub_ld(a_);                                                    \
          while ((uint32_t)(w_ >> 32) != (uint32_t)t) {                       \
            __builtin_amdgcn_s_sleep(1);                                      \
            w_ = pub_ld(a_);                                                  \
          }                                                                   \
        }                                                                     \
        RVQ = __uint_as_float((uint32_t)w_);                                  \
      }                                                                       \
      if (duty) {  /* rotating output duty, off other blocks' path */         \
        float v_ = RVQ * who_f;                                               \
        for (int o_ = 32; o_ > 0; o_ >>= 1) v_ += __shfl_down(v_, o_);        \
        if (lane == 0) obufd[(Q)][wv] = v_;                                   \
      }                                                                       \
    }                                                                         \
    /* matvec: wave wv = 64-i chunk; lane's column = ownLo + (lane & 31);     \
       full sequential 64-k chunk per lane -> bit-identical FP order. */      \
    {                                                                         \
      float acc_ = 0.0f;                                                      \
      _Pragma("unroll")                                                       \
      for (int k_ = 0; k_ < 64; ++k_) {                                       \
        float rk_ = __uint_as_float(                                          \
            __builtin_amdgcn_readlane(__float_as_uint(RVQ), k_));             \
        acc_ = fmaf(rk_, wJ[k_], acc_);                                       \
      }                                                                       \
      if (lane < 32) red[(Q) & 1][wv][lane] = acc_;                           \
    }                                                                         \
    NOISE_IF_PHASE0(Q)                                                        \
    barrier_lds();  /* the only barrier per phase */                          \
    if ((tid >> 5) == (Q)) {  /* 32 owner threads of batch Q */               \
      const int c_ = tid & 31;                                                \
      const int jown_ = ownLo + c_;                                           \
      float acc = red[(Q) & 1][0][c_];                                        \
      _Pragma("unroll")                                                       \
      for (int w2_ = 1; w2_ < 8; ++w2_) acc += red[(Q) & 1][w2_][c_];         \
      float nr  = nbuf[t & 3][(Q)][c_];                                       \
      float ni0 = ninb[t & 3][(Q)][0];                                        \
      float ni1 = ninb[t & 3][(Q)][1];                                        \
      float hid_hid = acc + bhh + REC_SCALE_F * nr;                           \
      float cur0 = fmaxf(stim_s[(Q)][t] + IN_SCALE_F * ni0, 0.0f);            \
      float cur1 = fmaxf(cc_s[(Q)][t]   + IN_SCALE_F * ni1, 0.0f);            \
      float hid_in = cur0 * wih0 + cur1 * wih1;                               \
      h = h + (-h + hid_in + hid_hid) * ALPHA_F;                              \
      float r_ = fmaxf(h, 0.0f);                                              \
      __hip_atomic_store(pub + (((t + 1) & 1) ? PUBH : 0)                     \
                             + (size_t)bQ * HH + jown_,                       \
                         ((uint64_t)(uint32_t)(t + 1) << 32) |                \
                             (uint64_t)__float_as_uint(r_),                   \
                         __ATOMIC_RELAXED, __HIP_MEMORY_SCOPE_AGENT);         \
      rloc[(Q)][c_] = r_;                                                     \
      __builtin_nontemporal_store(h, hids + ((size_t)bQ * TT + t) * HH        \
                                        + jown_);                             \
    }                                                                         \
    if (t > 0 && duty && tid == finTid) {                                     \
      const float* ob = obufd[(Q)];                                           \
      float p_ = ((ob[0] + ob[1]) + (ob[2] + ob[3])) +                        \
                 ((ob[4] + ob[5]) + (ob[6] + ob[7]));                         \
      outs[bQ * TT + (t - 1)] = p_ + bho;                                     \
    }                                                                         \
    if (!isOwnSlice) {  /* prefetch batch (Q+2)&3, 2 phases before consume */ \
      const uint32_t tau_ = ((Q) < 2) ? (uint32_t)t : (uint32_t)(t + 1);      \
      PREPF = pub_ld(pub + ((tau_ & 1) ? PUBH : 0)                            \
                     + (size_t)(b0 + (((Q) + 2) & 3)) * HH + tid);            \
    }                                                                         \
  }

// Tail consume of tag TT for the final output scalar.
#define TAILP(Q, RVQ, PREQ)                                                   \
  {                                                                           \
    const int bQ = b0 + (Q);                                                  \
    if (isOwnSlice) {                                                         \
      RVQ = rloc[(Q)][tid - ownLo];                                           \
    } else {                                                                  \
      uint64_t w_ = PREQ;                                                     \
      if ((uint32_t)(w_ >> 32) != (uint32_t)TT) {                             \
        const uint64_t* a_ = pub + ((TT & 1) ? PUBH : 0)                      \
                             + (size_t)bQ * HH + tid;                         \
        w_ = pub_ld(a_);                                                      \
        while ((uint32_t)(w_ >> 32) != (uint32_t)TT) {                        \
          __builtin_amdgcn_s_sleep(1);                                        \
          w_ = pub_ld(a_);                                                    \
        }                                                                     \
      }                                                                       \
      RVQ = __uint_as_float((uint32_t)w_);                                    \
    }                                                                         \
    float v_ = RVQ * who_f;                                                   \
    for (int o_ = 32; o_ > 0; o_ >>= 1) v_ += __shfl_down(v_, o_);            \
    if (lane == 0) obufd[(Q)][wv] = v_;                                       \
  }

__global__ __launch_bounds__(512, 2)
void zrnn_main(const float* __restrict__ i_stim, const float* __restrict__ i_cc,
               const float* __restrict__ hidden0,
               const float* __restrict__ w_ih, const float* __restrict__ w_hh,
               const float* __restrict__ b_hh,
               const float* __restrict__ w_ho, const float* __restrict__ b_ho,
               float* __restrict__ outs, float* __restrict__ hids,
               uint64_t* __restrict__ pub) {
  // bid = g*16 + s: group g (batches 4g..4g+3), slice s (cols [32s, 32s+32)).
  const int bid  = blockIdx.x;
  const int g    = bid >> 4;
  const int s    = bid & 15;
  const int b0   = g * NBAT;
  const int tid  = threadIdx.x;
  const int lane = tid & 63;
  const int wv   = tid >> 6;

  const int  ownLo      = s * SL;
  const bool isOwnSlice = (tid >= ownLo) && (tid < ownLo + SL);
  const int  finTid     = 320;   // plain consumer thread finalizes duty outs

  __shared__ float stim_s[NBAT][TT];   // 32 KB
  __shared__ float cc_s[NBAT][TT];     // 32 KB
  __shared__ float red[2][8][SL];      // phase-parity matvec partials
  __shared__ float rloc[NBAT][SL];     // own-slice relu(h) fast path
  __shared__ float nbuf[4][NBAT][SL];  // n_rec, generated 2 rounds ahead
  __shared__ float ninb[4][NBAT][2];   // n_in
  __shared__ float obufd[NBAT][8];     // duty output partials

  // Preload the group's input streams (owners then never touch global loads).
  #pragma unroll
  for (int q = 0; q < NBAT; ++q)
    for (int idx = tid; idx < TT; idx += 512) {
      stim_s[q][idx] = i_stim[(b0 + q) * TT + idx];
      cc_s[q][idx]   = i_cc[(b0 + q) * TT + idx];
    }

  // Weights (batch-invariant): thread (wv, lane) holds wt[i][jA] for
  // i in [64wv, 64wv+64), jA = ownLo + (lane & 31)  (half-waves replicate).
  // wt[i][j] = |w_hh[j][i]| * (i != j) * ei[i].
  const int jA = ownLo + (lane & 31);
  const int i0 = wv * 64;
  float wJ[64];
  #pragma unroll
  for (int k4 = 0; k4 < 16; ++k4) {
    float4 a4 = *reinterpret_cast<const float4*>(&w_hh[jA * HH + i0 + k4 * 4]);
    const float av[4] = {a4.x, a4.y, a4.z, a4.w};
    #pragma unroll
    for (int c = 0; c < 4; ++c) {
      const int i = i0 + k4 * 4 + c;
      float va = (i == jA) ? 0.0f : fabsf(av[c]);
      wJ[k4 * 4 + c] = (i < NEXC) ? va : -va;
    }
  }

  // Owners: tid < 128 owns (batch Q = tid>>5, col jown = ownLo + (tid&31)).
  float h = 0.f, wih0 = 0.f, wih1 = 0.f, bhh = 0.f;
  if (tid < NBAT * SL) {
    const int oq = tid >> 5, jg = ownLo + (tid & 31);
    h    = hidden0[(b0 + oq) * HH + jg];
    wih0 = w_ih[jg * 2 + 0];
    wih1 = w_ih[jg * 2 + 1];
    bhh  = b_hh[jg];
  }
  const float who_f = w_ho[tid];
  const float bho   = b_ho[0];

  // rv registers: thread tid holds relu(h[i = tid]) per batch.
  float rv0 = fmaxf(hidden0[(b0 + 0) * HH + tid], 0.f);
  float rv1 = fmaxf(hidden0[(b0 + 1) * HH + tid], 0.f);
  float rv2 = fmaxf(hidden0[(b0 + 2) * HH + tid], 0.f);
  float rv3 = fmaxf(hidden0[(b0 + 3) * HH + tid], 0.f);

  // Noise prefill for rounds 0,1 (slots 0,1): 256 n_rec + 16 n_in.
  if (tid < 256) {
    const int tp = tid >> 7, rem = tid & 127;
    const int qn = rem >> 5, jn = rem & 31;
    nbuf[tp][qn][jn] = jax_normal(KRC0, KRC1,
        (uint32_t)tp * (uint32_t)(BB * HH) +
        (uint32_t)((b0 + qn) * HH + ownLo + jn));
  } else if (tid < 272) {
    const int e = tid - 256;
    const int tp = e >> 3, qn = (e >> 1) & 3, sl = e & 1;
    ninb[tp][qn][sl] = jax_normal(KIN0, KIN1,
        (uint32_t)(tp * (BB * 2) + (b0 + qn) * 2 + sl));
  }

  uint64_t pre0 = 0, pre1 = 0, pre2 = 0, pre3 = 0;

  __syncthreads();

  for (int t = 0; t < TT; ++t) {
    const bool duty = (t > 0) && (s == ((t - 1) & 15));

    PHASE(0, rv0, pre0, pre2)
    PHASE(1, rv1, pre1, pre3)
    PHASE(2, rv2, pre2, pre0)
    PHASE(3, rv3, pre3, pre1)
  }

  // Tail: outs[.][TT-1] needs tag TT; duty slice (TT-1)&15 only.
  __syncthreads();
  if (s == ((TT - 1) & 15)) {
    TAILP(0, rv0, pre0)
    TAILP(1, rv1, pre1)
    TAILP(2, rv2, pre2)
    TAILP(3, rv3, pre3)
    __syncthreads();
    if (tid < NBAT) {
      const float* ob = obufd[tid];
      float p_ = ((ob[0] + ob[1]) + (ob[2] + ob[3])) +
                 ((ob[4] + ob[5]) + (ob[6] + ob[7]));
      outs[(b0 + tid) * TT + (TT - 1)] = p_ + bho;
    }
  }
}

extern "C" void kernel_launch(void* const* d_in, const int* in_sizes, int n_in,
                              void* d_out, int out_size, void* d_ws, size_t ws_size,
                              hipStream_t stream) {
  const float* i_stim = (const float*)d_in[0];
  const float* i_cc   = (const float*)d_in[1];
  const float* hidden = (const float*)d_in[2];
  const float* w_ih   = (const float*)d_in[3];
  // d_in[4] = b_ih — never used by the reference
  const float* w_hh   = (const float*)d_in[5];
  const float* b_hh   = (const float*)d_in[6];
  const float* w_ho   = (const float*)d_in[7];
  const float* b_ho   = (const float*)d_in[8];

  float* outs   = (float*)d_out;                     // [B,T,O]
  float* hids   = (float*)d_out + (size_t)BB * TT;   // [B,T,H]
  uint64_t* pub = (uint64_t*)d_ws;

  // Kill stale tags from previous graph replays (tags strictly increase
  // within a run, so zeroed words can never falsely match).
  hipMemsetAsync(pub, 0, PUB_BYTES, stream);

  void* args[] = {(void*)&i_stim, (void*)&i_cc, (void*)&hidden, (void*)&w_ih,
                  (void*)&w_hh, (void*)&b_hh, (void*)&w_ho, (void*)&b_ho,
                  (void*)&outs, (void*)&hids, (void*)&pub};
  hipLaunchCooperativeKernel((const void*)zrnn_main, dim3(NBLK), dim3(512),
                             args, 0, stream);
}

// Round 12
// 3889.918 us; speedup vs baseline: 3.1610x; 2.4579x over previous
//
#include <hip/hip_runtime.h>
#include <stdint.h>
#include <math.h>

#define HH   512
#define BB   64
#define TT   2000
#define NEXC 409          // int(0.8 * 512)
#define SLICE  128        // hidden units owned per block
#define NBLK   (BB * 4)   // 256 blocks = 1 per CU

// Python-float constants, rounded to f32 exactly as the reference does.
constexpr float ALPHA_F     = 0.1f;
constexpr float IN_SCALE_F  = (float)4.4721359549995794e-03;
constexpr float REC_SCALE_F = (float)4.4721359549995794e-02;
constexpr float SQRT2_F     = 1.41421356237309515f;
constexpr float U_LO        = -0x1.fffffep-1f;

struct U2 { uint32_t a, b; };

__host__ __device__ constexpr uint32_t rotl32(uint32_t x, int d) {
  return (x << d) | (x >> (32 - d));
}

// JAX Threefry-2x32, 20 rounds.
__host__ __device__ constexpr U2 tf2x32(uint32_t k0, uint32_t k1,
                                        uint32_t x0, uint32_t x1) {
  uint32_t ks[3] = {k0, k1, k0 ^ k1 ^ 0x1BD11BDAu};
  const int R[2][4] = {{13, 15, 26, 6}, {17, 29, 16, 24}};
  x0 += ks[0]; x1 += ks[1];
  for (int g = 0; g < 5; ++g) {
    const int* r = R[g & 1];
    for (int i = 0; i < 4; ++i) { x0 += x1; x1 = rotl32(x1, r[i]); x1 ^= x0; }
    x0 += ks[(g + 1) % 3];
    x1 += ks[(g + 2) % 3] + (uint32_t)(g + 1);
  }
  return U2{x0, x1};
}

constexpr U2 KIN_  = tf2x32(0u, 42u, 0u, 0u);
constexpr U2 KREC_ = tf2x32(0u, 42u, 0u, 1u);
constexpr uint32_t KIN0 = KIN_.a,  KIN1 = KIN_.b;
constexpr uint32_t KRC0 = KREC_.a, KRC1 = KREC_.b;

__device__ __forceinline__ float jax_normal(uint32_t k0, uint32_t k1, uint32_t idx) {
  U2 o = tf2x32(k0, k1, 0u, idx);
  uint32_t bits = o.a ^ o.b;
  float f = __uint_as_float((bits >> 9) | 0x3f800000u) - 1.0f;  // [0,1)
  float u = fmaxf(U_LO, f * 2.0f + U_LO);
  float w = -log1pf(-u * u);
  float p;
  if (w < 5.0f) {
    w = w - 2.5f;
    p =             2.81022636e-08f;
    p = fmaf(p, w,  3.43273939e-07f);
    p = fmaf(p, w, -3.5233877e-06f);
    p = fmaf(p, w, -4.39150654e-06f);
    p = fmaf(p, w,  0.00021858087f);
    p = fmaf(p, w, -0.00125372503f);
    p = fmaf(p, w, -0.00417768164f);
    p = fmaf(p, w,  0.246640727f);
    p = fmaf(p, w,  1.50140941f);
  } else {
    w = sqrtf(w) - 3.0f;
    p =            -0.000200214257f;
    p = fmaf(p, w,  0.000100950558f);
    p = fmaf(p, w,  0.00134934322f);
    p = fmaf(p, w, -0.00367342844f);
    p = fmaf(p, w,  0.00573950773f);
    p = fmaf(p, w, -0.0076224613f);
    p = fmaf(p, w,  0.00943887047f);
    p = fmaf(p, w,  1.00167406f);
    p = fmaf(p, w,  2.83297682f);
  }
  return SQRT2_F * (p * u);
}

// Workspace: pub[4][BB][HH] uint64 words = 1 MB. word = (tag<<32)|f32bits(relu(h)).
// Slot = t & 3 holds tag t+1: 4-deep so same-address rewrites are >= 4 tags
// apart (safety margin for in-flight stores now that barriers don't drain vmcnt;
// causal lag between sibling blocks is provably < 2 tags).
#define PUB_SLOT  ((size_t)(BB * HH))
#define PUB_BYTES (4 * BB * HH * 8)   // 1 MB

// LDS-only barrier: orders all LDS traffic (red/rloc/obuf) across the block
// but does NOT drain vmcnt — publish + hids stores stay in flight
// (fire-and-forget; no thread in this block ever reads them).
__device__ __forceinline__ void barrier_lds() {
  asm volatile("s_waitcnt lgkmcnt(0)" ::: "memory");
  __builtin_amdgcn_s_barrier();
  asm volatile("" ::: "memory");
}

__device__ __forceinline__ uint64_t pub_ld(const uint64_t* a) {
  return __hip_atomic_load(a, __ATOMIC_RELAXED, __HIP_MEMORY_SCOPE_AGENT);
}

__global__ __launch_bounds__(512, 2)
void zrnn_main(const float* __restrict__ i_stim, const float* __restrict__ i_cc,
               const float* __restrict__ hidden0,
               const float* __restrict__ w_ih, const float* __restrict__ w_hh,
               const float* __restrict__ b_hh,
               const float* __restrict__ w_ho, const float* __restrict__ b_ho,
               float* __restrict__ outs, float* __restrict__ hids,
               uint64_t* __restrict__ pub) {
  // blockIdx -> (batch b, slice s); same-batch siblings share blockIdx%8 so they
  // land on one XCD under round-robin dispatch (perf-only assumption).
  const int bid  = blockIdx.x;
  const int low3 = bid & 7;
  const int q    = bid >> 3;
  const int s    = q & 3;
  const int b    = ((q >> 2) << 3) + low3;
  const int tid  = threadIdx.x;
  const int lane = tid & 63;
  const int wv   = tid >> 6;          // wave id = i-chunk id

  __shared__ float stim_s[TT];
  __shared__ float cc_s[TT];
  __shared__ float red[8][SLICE];     // per-wave matvec partials
  __shared__ float rloc[SLICE];       // own-slice relu(h) fast path (skip MALL)
  __shared__ float nbuf[4][SLICE];    // n_rec, 4 steps ahead
  __shared__ float nin_s[4][2];       // n_in,  4 steps ahead
  __shared__ float obuf[8];           // block-0 output partials

  // Preload this batch's input streams (16 KB LDS), coalesced.
  for (int idx = tid; idx < TT; idx += 512) {
    stim_s[idx] = i_stim[b * TT + idx];
    cc_s[idx]   = i_cc[b * TT + idx];
  }

  // Weight slice in REGISTERS: thread (wv,lane) holds wt[i][j] for
  // i in [64*wv, 64*wv+64), j in {jA, jB}.  wt[i][j] = |w_hh[j][i]|*(i!=j)*ei[i].
  const int jA = s * SLICE + lane;
  const int jB = jA + 64;
  const int i0 = wv * 64;
  float wA[64], wB[64];
  #pragma unroll
  for (int k4 = 0; k4 < 16; ++k4) {
    float4 a4 = *reinterpret_cast<const float4*>(&w_hh[jA * HH + i0 + k4 * 4]);
    float4 b4 = *reinterpret_cast<const float4*>(&w_hh[jB * HH + i0 + k4 * 4]);
    const float av[4] = {a4.x, a4.y, a4.z, a4.w};
    const float bv[4] = {b4.x, b4.y, b4.z, b4.w};
    #pragma unroll
    for (int c = 0; c < 4; ++c) {
      const int i = i0 + k4 * 4 + c;
      float va = (i == jA) ? 0.0f : fabsf(av[c]);
      float vb = (i == jB) ? 0.0f : fabsf(bv[c]);
      wA[k4 * 4 + c] = (i < NEXC) ? va : -va;
      wB[k4 * 4 + c] = (i < NEXC) ? vb : -vb;
    }
  }

  // Hidden-state owners: threads 0..127 own j = s*128 + tid.
  float h = 0.0f, wih0 = 0.0f, wih1 = 0.0f, bhh = 0.0f;
  const int jown = s * SLICE + tid;
  if (tid < SLICE) {
    h    = hidden0[b * HH + jown];
    wih0 = w_ih[jown * 2 + 0];
    wih1 = w_ih[jown * 2 + 1];
    bhh  = b_hh[jown];
  }
  // Block s==0 computes the output scalar from its full rv vector.
  float who_f = 0.0f, bho = 0.0f;
  if (s == 0) { who_f = w_ho[tid]; bho = b_ho[0]; }

  // rv: lane mapping i = tid; primed from hidden0.
  float rv = fmaxf(hidden0[b * HH + tid], 0.0f);

  // Noise prefill for steps 0..3.
  {
    const int tp = tid >> 7;
    const int jn = tid & 127;
    nbuf[tp][jn] = jax_normal(KRC0, KRC1,
        (uint32_t)tp * (uint32_t)(BB * HH) + (uint32_t)(b * HH + s * SLICE + jn));
    if (tid < 8) {
      const int tp2  = tid >> 1;
      const int slot = tid & 1;
      nin_s[tp2][slot] = jax_normal(KIN0, KIN1,
          (uint32_t)(tp2 * (BB * 2) + b * 2 + slot));
    }
  }

  const int  ownLo     = s * SLICE;
  const bool isOwnLane = (tid >= ownLo) && (tid < ownLo + SLICE);
  float* __restrict__ hid_out = hids + (size_t)b * TT * HH;

  __syncthreads();

  for (int t = 0; t < TT; ++t) {
    // Block 0: previous step's output scalar from rv (tag t) — off critical path.
    if (s == 0 && t > 0) {
      float v = rv * who_f;
      #pragma unroll
      for (int off = 32; off > 0; off >>= 1) v += __shfl_down(v, off);
      if (lane == 0) obuf[wv] = v;
    }

    // A: matvec partials — readlane-broadcast rv, register weights.
    float accA = 0.0f, accB = 0.0f;
    #pragma unroll
    for (int k = 0; k < 64; ++k) {
      float rk = __uint_as_float(__builtin_amdgcn_readlane(__float_as_uint(rv), k));
      accA = fmaf(rk, wA[k], accA);
      accB = fmaf(rk, wB[k], accB);
    }
    red[wv][lane]      = accA;
    red[wv][64 + lane] = accB;
    barrier_lds();  // barrier 1: red ready (LDS only; no vmcnt drain)

    uint64_t* pub_t = pub + (size_t)(t & 3) * PUB_SLOT + (size_t)b * HH;

    // C: owners combine chunks (increasing-i), update h, publish tagged word.
    if (tid < SLICE) {
      float acc = red[0][tid];
      #pragma unroll
      for (int w = 1; w < 8; ++w) acc += red[w][tid];
      float nr = nbuf[t & 3][tid];
      float hid_hid = acc + bhh + REC_SCALE_F * nr;
      float ni0 = nin_s[t & 3][0];
      float ni1 = nin_s[t & 3][1];
      float cur0 = fmaxf(stim_s[t] + IN_SCALE_F * ni0, 0.0f);
      float cur1 = fmaxf(cc_s[t]   + IN_SCALE_F * ni1, 0.0f);
      float hid_in = cur0 * wih0 + cur1 * wih1;
      h = h + (-h + hid_in + hid_hid) * ALPHA_F;
      float r = fmaxf(h, 0.0f);
      uint64_t wd = ((uint64_t)(uint32_t)(t + 1) << 32) |
                    (uint64_t)__float_as_uint(r);
      __hip_atomic_store(&pub_t[jown], wd, __ATOMIC_RELAXED,
                         __HIP_MEMORY_SCOPE_AGENT);   // fire-and-forget
      rloc[tid] = r;
      __builtin_nontemporal_store(h, hid_out + (size_t)t * HH + jown);
      if (s == 0 && tid == 0 && t > 0) {
        float p = ((obuf[0] + obuf[1]) + (obuf[2] + obuf[3])) +
                  ((obuf[4] + obuf[5]) + (obuf[6] + obuf[7]));
        outs[b * TT + (t - 1)] = p + bho;
      }
    }
    barrier_lds();  // barrier 2: rloc ready; red free for reuse (LDS only)

    // F: overlap the wait with noise precompute for t+1..t+4.
    if ((t & 3) == 3 && t + 1 < TT) {
      const int tp = t + 1 + (tid >> 7);
      if (tp < TT) {
        const int jn = tid & 127;
        nbuf[tp & 3][jn] = jax_normal(KRC0, KRC1,
            (uint32_t)tp * (uint32_t)(BB * HH) + (uint32_t)(b * HH + s * SLICE + jn));
      }
      if (tid < 8) {
        const int tp2  = t + 1 + (tid >> 1);
        const int slot = tid & 1;
        if (tp2 < TT)
          nin_s[tp2 & 3][slot] = jax_normal(KIN0, KIN1,
              (uint32_t)(tp2 * (BB * 2) + b * 2 + slot));
      }
    }

    // H: refresh rv. Own slice via LDS; remote via PACED 2-deep tagged-word poll.
    if (isOwnLane) {
      rv = rloc[tid - ownLo];
    } else {
      const uint32_t tagw = (uint32_t)(t + 1);
      const uint64_t* a = &pub_t[tid];
      uint64_t w0 = pub_ld(a);
      if ((uint32_t)(w0 >> 32) != tagw) {
        uint64_t w1 = pub_ld(a);
        int it = 0;
        while ((uint32_t)(w0 >> 32) != tagw) {
          ++it;
          if (it > 64) __builtin_amdgcn_s_sleep(8);
          else         __builtin_amdgcn_s_sleep(1);
          w0 = w1;
          w1 = pub_ld(a);
        }
      }
      rv = __uint_as_float((uint32_t)w0);
    }
  }

  // Tail: outs[TT-1] from final rv (tag TT).
  if (s == 0) {
    float v = rv * who_f;
    #pragma unroll
    for (int off = 32; off > 0; off >>= 1) v += __shfl_down(v, off);
    if (lane == 0) obuf[wv] = v;
    __syncthreads();
    if (tid == 0) {
      float p = ((obuf[0] + obuf[1]) + (obuf[2] + obuf[3])) +
                ((obuf[4] + obuf[5]) + (obuf[6] + obuf[7]));
      outs[b * TT + (TT - 1)] = p + bho;
    }
  }
}

extern "C" void kernel_launch(void* const* d_in, const int* in_sizes, int n_in,
                              void* d_out, int out_size, void* d_ws, size_t ws_size,
                              hipStream_t stream) {
  const float* i_stim = (const float*)d_in[0];
  const float* i_cc   = (const float*)d_in[1];
  const float* hidden = (const float*)d_in[2];
  const float* w_ih   = (const float*)d_in[3];
  // d_in[4] = b_ih — never used by the reference
  const float* w_hh   = (const float*)d_in[5];
  const float* b_hh   = (const float*)d_in[6];
  const float* w_ho   = (const float*)d_in[7];
  const float* b_ho   = (const float*)d_in[8];

  float* outs   = (float*)d_out;                     // [B,T,O]
  float* hids   = (float*)d_out + (size_t)BB * TT;   // [B,T,H]
  uint64_t* pub = (uint64_t*)d_ws;

  // Kill stale tags from previous graph replays (tags strictly increase
  // within a run, so zeroed words can never falsely match).
  hipMemsetAsync(pub, 0, PUB_BYTES, stream);

  void* args[] = {(void*)&i_stim, (void*)&i_cc, (void*)&hidden, (void*)&w_ih,
                  (void*)&w_hh, (void*)&b_hh, (void*)&w_ho, (void*)&b_ho,
                  (void*)&outs, (void*)&hids, (void*)&pub};
  hipLaunchCooperativeKernel((const void*)zrnn_main, dim3(NBLK), dim3(512),
                             args, 0, stream);
}